// Round 8
// baseline (286.018 us; speedup 1.0000x reference)
//
#include <hip/hip_runtime.h>

// B=128, N=256, D=O=512. R = B*N = 32768 rows.
// Pipeline (3 kernels):
//   prep_w:  W -> chunk-tiled W^T f16: WTc[g][c][o][32], c = K-chunk of 32.
//   mega:    per 64-row slab: LN1(Obs)->sX, then {GEMM1+tanh -> h1(regs) ->
//            LN2 -> sX, GEMM2+tanh+h1 -> LN3 -> sX, GEMM3 -> logits fp32}.
//   softmax: masked softmax over N, register-resident, single-exp.
// mega: 512 threads, 8 waves, per-wave 64 rows x 64 cols (acc[4][4] in AGPRs,
// ~192 total regs/wave -> 8 waves/CU; next occupancy cliff at 256 regs, so
// registers up to 256 are free). Rounds 4/6/7 (identical 161us, MfmaUtil 13%,
// ~70% no-issue cycles) showed the binding constraint is LATENCY EXPOSURE at
// prefetch distance 1, not traffic and not occupancy knobs. This round:
// B-prefetch deepened to distance 2 (triple-buffered bfA/bfB/bfC, fully
// static 16-step K-loop; in-flight = 8 loads) so steady-state L2 latency
// (~300cy) is covered by 2 steps of MFMA pipe time (~320cy).
// K-loop stays barrier-free: per-wave B slices from L2-hot WTc (coalesced
// 1 KB/wave-instr). A in LDS, XS=520 stride (mild 1.5x bank aliasing).

#define NN 256

typedef _Float16 f16;
typedef __attribute__((ext_vector_type(4))) _Float16 f16x4;
typedef __attribute__((ext_vector_type(8))) _Float16 f16x8;
typedef __attribute__((ext_vector_type(4))) float f32x4;

#define XS    520   // sX row stride (f16)
#define EPS32 516   // f32 logits epilogue stride

__device__ __forceinline__ float fast_tanh(float x) {
  float e = __expf(2.f * x);
  return 1.f - 2.f * __builtin_amdgcn_rcpf(e + 1.f);
}

// ---- W[d][o] fp32 -> WTc[g][c][o][dlow] f16 (chunk-tiled transpose) ----
__global__ void prep_w_kernel(const float* __restrict__ W1, const float* __restrict__ W2,
                              const float* __restrict__ W3, f16* __restrict__ WTc) {
  int idx = blockIdx.x * 256 + threadIdx.x;
  int g    = idx >> 18;
  int rem  = idx & 0x3FFFF;
  int c    = rem >> 14;          // K-chunk (16 of them)
  int o    = (rem >> 5) & 511;   // output col
  int dlow = rem & 31;           // k within chunk
  const float* W = (g == 0) ? W1 : (g == 1) ? W2 : W3;
  WTc[idx] = (f16)W[(c * 32 + dlow) * 512 + o];
}

// load one chunk's B fragments (4 x global_load_dwordx4, contiguous 1 KB/wave)
__device__ __forceinline__ void load_bf(f16x8 bf[4], const f16* __restrict__ bw, int c) {
  #pragma unroll
  for (int i = 0; i < 4; ++i)
    bf[i] = *(const f16x8*)(bw + c * 16384 + i * 512);
}

// one K-step: 4 ds_read_b128 of A fragments + 16 MFMA against preloaded bf
__device__ __forceinline__ void gemm_step(f32x4 acc[4][4], const f16* __restrict__ sXb,
                                          const f16x8 bf[4], int c) {
  f16x8 af[4];
  #pragma unroll
  for (int i = 0; i < 4; ++i)
    af[i] = *(const f16x8*)&sXb[i * 16 * XS + c * 32];
  #pragma unroll
  for (int mi = 0; mi < 4; ++mi)
    #pragma unroll
    for (int ni = 0; ni < 4; ++ni)
      acc[mi][ni] = __builtin_amdgcn_mfma_f32_16x16x32_f16(af[mi], bf[ni], acc[mi][ni], 0, 0, 0);
}

// ---- Mega kernel: LN1 + 3 GEMMs + 2 LNs + tanh + residual, one 64-row slab ----
__global__ __attribute__((amdgpu_flat_work_group_size(512, 512), amdgpu_waves_per_eu(2, 2)))
void mega_kernel(
    const float* __restrict__ Obs,
    const float* __restrict__ g1, const float* __restrict__ b1,
    const f16* __restrict__ WTc,
    const float* __restrict__ g2, const float* __restrict__ b2,
    const float* __restrict__ g3, const float* __restrict__ b3,
    float* __restrict__ outF) {
  __shared__ __align__(16) char smem[71168];
  f16* sX = (f16*)smem;                        // [64][XS] activations (A operand)
  float2* sPart = (float2*)(smem + 66560);     // [512] per-wave LN partials
  float2* sStat = (float2*)(smem + 70656);     // [64] (mean, inv) per row

  int t = threadIdx.x, lane = t & 63, wv = t >> 6;
  int row16 = lane & 15, quad = lane >> 4;
  int rBase = blockIdx.x * 64;

  // per-lane bases
  const f16* sXb = sX + row16 * XS + quad * 8;                 // A fragment base
  // B fragment base: chunk-tiled. Wave's cols wv*64.., lane covers
  // row16*64B + quad*16B of the contiguous [16 rows][32 f16] = 1 KB segment.
  const f16* bw = WTc + wv * 2048 + row16 * 32 + quad * 8;

  f32x4 acc[4][4];
  f16x8 bfA[4], bfB[4], bfC[4];   // triple buffer: 2 chunks in flight
  f16x4 h1s[4][4];   // residual tanh(A1@W1), register-resident across GEMM2

  // preload GEMM1 chunks 0,1 (arrive during the LN1 prologue)
  load_bf(bfA, bw, 0);
  load_bf(bfB, bw, 1);

  // ---- LN1 prologue: each wave normalizes its 8 rows of Obs into sX ----
  {
    float4 w0 = *(const float4*)(g1 + lane * 4);
    float4 u0 = *(const float4*)(b1 + lane * 4);
    float4 w1 = *(const float4*)(g1 + 256 + lane * 4);
    float4 u1 = *(const float4*)(b1 + 256 + lane * 4);
    #pragma unroll
    for (int p = 0; p < 8; ++p) {
      int row = wv * 8 + p;
      const float* x = Obs + (((size_t)(rBase + row)) << 9);
      float4 v0 = *(const float4*)(x + lane * 4);
      float4 v1 = *(const float4*)(x + 256 + lane * 4);
      float s = v0.x + v0.y + v0.z + v0.w + v1.x + v1.y + v1.z + v1.w;
      float q = v0.x*v0.x + v0.y*v0.y + v0.z*v0.z + v0.w*v0.w
              + v1.x*v1.x + v1.y*v1.y + v1.z*v1.z + v1.w*v1.w;
      #pragma unroll
      for (int off = 1; off < 64; off <<= 1) {
        s += __shfl_xor(s, off, 64);
        q += __shfl_xor(q, off, 64);
      }
      float mean = s * (1.f / 512.f);
      float var  = q * (1.f / 512.f) - mean * mean;
      float inv  = 1.f / sqrtf(var + 1e-5f);
      f16x4 o0, o1;
      o0[0] = (f16)((v0.x - mean) * inv * w0.x + u0.x);
      o0[1] = (f16)((v0.y - mean) * inv * w0.y + u0.y);
      o0[2] = (f16)((v0.z - mean) * inv * w0.z + u0.z);
      o0[3] = (f16)((v0.w - mean) * inv * w0.w + u0.w);
      o1[0] = (f16)((v1.x - mean) * inv * w1.x + u1.x);
      o1[1] = (f16)((v1.y - mean) * inv * w1.y + u1.y);
      o1[2] = (f16)((v1.z - mean) * inv * w1.z + u1.z);
      o1[3] = (f16)((v1.w - mean) * inv * w1.w + u1.w);
      *(f16x4*)&sX[row * XS + lane * 4] = o0;
      *(f16x4*)&sX[row * XS + 256 + lane * 4] = o1;
    }
  }
  __syncthreads();   // sX (A1) ready for all waves

  for (int g = 0; g < 3; ++g) {
    #pragma unroll
    for (int mi = 0; mi < 4; ++mi)
      #pragma unroll
      for (int ni = 0; ni < 4; ++ni)
        acc[mi][ni] = (f32x4){0.f, 0.f, 0.f, 0.f};

    // K-loop: barrier-free, distance-2 prefetch, fully static buffer rotation.
    // Step c consumes buffer (c%3); immediately after, that buffer is refilled
    // with chunk c+3. In flight: chunks c+1, c+2 (8 loads).
    load_bf(bfC, bw, 2);
    gemm_step(acc, sXb, bfA, 0);   load_bf(bfA, bw, 3);
    gemm_step(acc, sXb, bfB, 1);   load_bf(bfB, bw, 4);
    gemm_step(acc, sXb, bfC, 2);   load_bf(bfC, bw, 5);
    gemm_step(acc, sXb, bfA, 3);   load_bf(bfA, bw, 6);
    gemm_step(acc, sXb, bfB, 4);   load_bf(bfB, bw, 7);
    gemm_step(acc, sXb, bfC, 5);   load_bf(bfC, bw, 8);
    gemm_step(acc, sXb, bfA, 6);   load_bf(bfA, bw, 9);
    gemm_step(acc, sXb, bfB, 7);   load_bf(bfB, bw, 10);
    gemm_step(acc, sXb, bfC, 8);   load_bf(bfC, bw, 11);
    gemm_step(acc, sXb, bfA, 9);   load_bf(bfA, bw, 12);
    gemm_step(acc, sXb, bfB, 10);  load_bf(bfB, bw, 13);
    gemm_step(acc, sXb, bfC, 11);  load_bf(bfC, bw, 14);
    gemm_step(acc, sXb, bfA, 12);  load_bf(bfA, bw, 15);
    gemm_step(acc, sXb, bfB, 13);
    gemm_step(acc, sXb, bfC, 14);
    gemm_step(acc, sXb, bfA, 15);

    if (g == 2) {
      __syncthreads();   // all waves done reading sX -> safe to overlay sE
      float* sE = (float*)smem;
      #pragma unroll
      for (int half = 0; half < 2; ++half) {
        #pragma unroll
        for (int mi = 0; mi < 2; ++mi) {
          int rt = half * 2 + mi;
          #pragma unroll
          for (int ni = 0; ni < 4; ++ni) {
            int col = wv * 64 + ni * 16 + row16;
            #pragma unroll
            for (int rg = 0; rg < 4; ++rg)
              sE[(mi * 16 + quad * 4 + rg) * EPS32 + col] = acc[rt][ni][rg];
          }
        }
        __syncthreads();
        #pragma unroll
        for (int i = 0; i < 8; ++i) {
          int gi = t + i * 512;
          int row = gi >> 7, cg = (gi & 127) * 4;
          f32x4 v = *(const f32x4*)&sE[row * EPS32 + cg];
          *(f32x4*)&outF[(((size_t)(rBase + half * 32 + row)) << 9) + cg] = v;
        }
        __syncthreads();
      }
    } else {
      // tanh
      #pragma unroll
      for (int mi = 0; mi < 4; ++mi)
        #pragma unroll
        for (int ni = 0; ni < 4; ++ni)
          #pragma unroll
          for (int rg = 0; rg < 4; ++rg)
            acc[mi][ni][rg] = fast_tanh(acc[mi][ni][rg]);

      if (g == 0) {
        // stash h1 (same (row,col) mapping as GEMM2's acc)
        #pragma unroll
        for (int mi = 0; mi < 4; ++mi)
          #pragma unroll
          for (int ni = 0; ni < 4; ++ni) {
            f16x4 h;
            #pragma unroll
            for (int rg = 0; rg < 4; ++rg) h[rg] = (f16)acc[mi][ni][rg];
            h1s[mi][ni] = h;
          }
      } else {
        // residual: h2 + h1
        #pragma unroll
        for (int mi = 0; mi < 4; ++mi)
          #pragma unroll
          for (int ni = 0; ni < 4; ++ni)
            #pragma unroll
            for (int rg = 0; rg < 4; ++rg)
              acc[mi][ni][rg] += (float)h1s[mi][ni][rg];
      }

      const float* gp = (g == 0) ? g2 : g3;
      const float* bp = (g == 0) ? b2 : b3;
      float gva[4], bva[4];
      #pragma unroll
      for (int ni = 0; ni < 4; ++ni) {
        int col = wv * 64 + ni * 16 + row16;
        gva[ni] = gp[col]; bva[ni] = bp[col];
      }

      // per-row LN stats: lane partial over ni, butterfly over 16-lane groups
      #pragma unroll
      for (int mi = 0; mi < 4; ++mi)
        #pragma unroll
        for (int rg = 0; rg < 4; ++rg) {
          float s = 0.f, q = 0.f;
          #pragma unroll
          for (int ni = 0; ni < 4; ++ni) {
            float v = acc[mi][ni][rg];
            s += v; q += v * v;
          }
          #pragma unroll
          for (int off = 1; off < 16; off <<= 1) {
            s += __shfl_xor(s, off, 16);
            q += __shfl_xor(q, off, 16);
          }
          if (row16 == 0)
            sPart[wv * 64 + mi * 16 + quad * 4 + rg] = make_float2(s, q);
        }
      __syncthreads();   // sPart ready; also: all waves done reading sX
      if (t < 64) {
        float s = 0.f, q = 0.f;
        #pragma unroll
        for (int w = 0; w < 8; ++w) {
          float2 p = sPart[w * 64 + t];
          s += p.x; q += p.y;
        }
        float mean = s * (1.f / 512.f);
        float var  = q * (1.f / 512.f) - mean * mean;
        sStat[t] = make_float2(mean, 1.f / sqrtf(var + 1e-5f));
      }

      // preload next GEMM's chunks 0,1 (covers L2 latency under LN epilogue)
      bw += 262144;
      load_bf(bfA, bw, 0);
      load_bf(bfB, bw, 1);

      __syncthreads();   // sStat ready

      // normalize -> write next A operand back into sX (in place)
      #pragma unroll
      for (int mi = 0; mi < 4; ++mi)
        #pragma unroll
        for (int rg = 0; rg < 4; ++rg) {
          int row = mi * 16 + quad * 4 + rg;
          float2 st = sStat[row];
          #pragma unroll
          for (int ni = 0; ni < 4; ++ni) {
            int col = wv * 64 + ni * 16 + row16;
            sX[row * XS + col] = (f16)((acc[mi][ni][rg] - st.x) * st.y * gva[ni] + bva[ni]);
          }
        }
      __syncthreads();   // sX ready for next GEMM
    }
  }
}

// ---- Masked softmax over N: register-resident. Block = (b, 64-o chunk). ----
// Thread (c4 = t&15, nh = t>>4) owns cols oc*64 + c4*4..+3, rows n = nh+16j.
// Single exp: p = exp(v-m) kept in regs, reused for sum and the final scale.
__global__ __launch_bounds__(256, 2) void softmax_kernel(const float* __restrict__ o3,
                                                         const int* __restrict__ mask,
                                                         float* __restrict__ out) {
  __shared__ float4 smx[16][16];   // [nh][c4] partial col-maxes
  __shared__ float4 sms[16][16];   // [nh][c4] partial col-sums
  __shared__ int    smask[NN];

  int b  = blockIdx.x >> 3;
  int oc = blockIdx.x & 7;
  int t  = threadIdx.x;
  int c4 = t & 15;
  int nh = t >> 4;

  const float4* src = (const float4*)(o3 + (((size_t)(b * NN)) << 9)) + oc * 16 + c4;
  float4 v[16];
  #pragma unroll
  for (int j = 0; j < 16; ++j)
    v[j] = src[(size_t)(nh + 16 * j) * 128];

  int mt = mask[b * NN + t];
  int any = __syncthreads_or(mt);
  smask[t] = (t == 0 && !any) ? 1 : mt;
  __syncthreads();

  const float NEG = -3.4e38f;
  #pragma unroll
  for (int j = 0; j < 16; ++j)
    if (!smask[nh + 16 * j]) v[j] = (float4){NEG, NEG, NEG, NEG};

  // col max over this thread's 16 rows, then over the 16 nh groups via LDS
  float4 m4 = v[0];
  #pragma unroll
  for (int j = 1; j < 16; ++j) {
    m4.x = fmaxf(m4.x, v[j].x); m4.y = fmaxf(m4.y, v[j].y);
    m4.z = fmaxf(m4.z, v[j].z); m4.w = fmaxf(m4.w, v[j].w);
  }
  smx[nh][c4] = m4;
  __syncthreads();
  float4 mm = smx[0][c4];
  #pragma unroll
  for (int k = 1; k < 16; ++k) {
    float4 o = smx[k][c4];
    mm.x = fmaxf(mm.x, o.x); mm.y = fmaxf(mm.y, o.y);
    mm.z = fmaxf(mm.z, o.z); mm.w = fmaxf(mm.w, o.w);
  }

  // p = exp(v - m) in-register (single exp), col sum
  float4 s4 = {0.f, 0.f, 0.f, 0.f};
  #pragma unroll
  for (int j = 0; j < 16; ++j) {
    v[j].x = __expf(v[j].x - mm.x); s4.x += v[j].x;
    v[j].y = __expf(v[j].y - mm.y); s4.y += v[j].y;
    v[j].z = __expf(v[j].z - mm.z); s4.z += v[j].z;
    v[j].w = __expf(v[j].w - mm.w); s4.w += v[j].w;
  }
  sms[nh][c4] = s4;
  __syncthreads();
  float4 tot = sms[0][c4];
  #pragma unroll
  for (int k = 1; k < 16; ++k) {
    float4 o = sms[k][c4];
    tot.x += o.x; tot.y += o.y; tot.z += o.z; tot.w += o.w;
  }
  float4 inv = {1.f / tot.x, 1.f / tot.y, 1.f / tot.z, 1.f / tot.w};

  float4* dst = (float4*)(out + (((size_t)(b * NN)) << 9)) + oc * 16 + c4;
  #pragma unroll
  for (int j = 0; j < 16; ++j) {
    float4 r;
    r.x = v[j].x * inv.x;
    r.y = v[j].y * inv.y;
    r.z = v[j].z * inv.z;
    r.w = v[j].w * inv.w;
    dst[(size_t)(nh + 16 * j) * 128] = r;
  }
}

extern "C" void kernel_launch(void* const* d_in, const int* in_sizes, int n_in,
                              void* d_out, int out_size, void* d_ws, size_t ws_size,
                              hipStream_t stream) {
  const float* Obs = (const float*)d_in[0];
  const int*   msk = (const int*)d_in[1];
  const float* g1  = (const float*)d_in[2];
  const float* b1  = (const float*)d_in[3];
  const float* W1  = (const float*)d_in[4];
  const float* g2  = (const float*)d_in[5];
  const float* b2  = (const float*)d_in[6];
  const float* W2  = (const float*)d_in[7];
  const float* g3  = (const float*)d_in[8];
  const float* b3  = (const float*)d_in[9];
  const float* W3  = (const float*)d_in[10];
  float* out = (float*)d_out;

  char* ws = (char*)d_ws;
  const size_t MB = 1u << 20;
  float* Lg = (float*)ws;                  // [0, 64M) logits fp32
  f16*   WTc = (f16*)(ws + 64 * MB);       // 1.5 MB chunk-tiled

  prep_w_kernel<<<3072, 256, 0, stream>>>(W1, W2, W3, WTc);
  mega_kernel<<<512, 512, 0, stream>>>(Obs, g1, b1, WTc, g2, b2, g3, b3, Lg);
  softmax_kernel<<<1024, 256, 0, stream>>>(Lg, msk, out);
}

// Round 9
// 274.159 us; speedup vs baseline: 1.0433x; 1.0433x over previous
//
#include <hip/hip_runtime.h>

// B=128, N=256, D=O=512. R = B*N = 32768 rows.
// Pipeline (3 kernels):
//   prep_w:  W -> chunk-tiled W^T f16: WTc[g][c][o][32], c = K-chunk of 32.
//   mega:    per 64-row slab: LN1(Obs)->sX, then {GEMM1+tanh -> h1(LDS) ->
//            LN2 -> sX, GEMM2+tanh+h1 -> LN3 -> sX, GEMM3 -> logits fp32}.
//   softmax: masked softmax over N, register-resident, single-exp.
// mega: 512 threads, 8 waves, per-wave 64 rows x 64 cols. acc[4][4] lives in
// 64 AGPRs; arch-VGPR allocation is pinned at 128 by the compiler (rounds
// 4/6/7: identical counters; round 8: +16 regs of prefetch buffers -> +67 MB
// scratch traffic -> CONFIRMED every live reg past 128 spills into the
// K-loop). Fix: h1 (32 VGPRs, written once / read once, no arithmetic reuse)
// moves to LDS sH[col][row] stride 66 -- writer lane == reader lane (same
// wv/row16/quad both phases), so no barriers needed; f16x4 access, <=2-way
// banks. Live set drops to ~112 < 128 -> no spills. K-loop: distance-1
// register double-buffer (round 6 schedule), barrier-free; B slices from
// L2-hot chunk-tiled WTc (coalesced 1 KB/wave-instr). A in LDS, XS=520.

#define NN 256

typedef _Float16 f16;
typedef __attribute__((ext_vector_type(4))) _Float16 f16x4;
typedef __attribute__((ext_vector_type(8))) _Float16 f16x8;
typedef __attribute__((ext_vector_type(4))) float f32x4;

#define XS    520   // sX row stride (f16)
#define HS    66    // sH row stride (f16), [512 cols][66 rows]
#define EPS32 516   // f32 logits epilogue stride

__device__ __forceinline__ float fast_tanh(float x) {
  float e = __expf(2.f * x);
  return 1.f - 2.f * __builtin_amdgcn_rcpf(e + 1.f);
}

// ---- W[d][o] fp32 -> WTc[g][c][o][dlow] f16 (chunk-tiled transpose) ----
__global__ void prep_w_kernel(const float* __restrict__ W1, const float* __restrict__ W2,
                              const float* __restrict__ W3, f16* __restrict__ WTc) {
  int idx = blockIdx.x * 256 + threadIdx.x;
  int g    = idx >> 18;
  int rem  = idx & 0x3FFFF;
  int c    = rem >> 14;          // K-chunk (16 of them)
  int o    = (rem >> 5) & 511;   // output col
  int dlow = rem & 31;           // k within chunk
  const float* W = (g == 0) ? W1 : (g == 1) ? W2 : W3;
  WTc[idx] = (f16)W[(c * 32 + dlow) * 512 + o];
}

// one K-step: 4 ds_read_b128 of A fragments + 16 MFMA against preloaded bf
__device__ __forceinline__ void gemm_step(f32x4 acc[4][4], const f16* __restrict__ sXb,
                                          const f16x8 bf[4], int c) {
  f16x8 af[4];
  #pragma unroll
  for (int i = 0; i < 4; ++i)
    af[i] = *(const f16x8*)&sXb[i * 16 * XS + c * 32];
  #pragma unroll
  for (int mi = 0; mi < 4; ++mi)
    #pragma unroll
    for (int ni = 0; ni < 4; ++ni)
      acc[mi][ni] = __builtin_amdgcn_mfma_f32_16x16x32_f16(af[mi], bf[ni], acc[mi][ni], 0, 0, 0);
}

// ---- Mega kernel: LN1 + 3 GEMMs + 2 LNs + tanh + residual, one 64-row slab ----
__global__ __attribute__((amdgpu_flat_work_group_size(512, 512), amdgpu_waves_per_eu(2, 2)))
void mega_kernel(
    const float* __restrict__ Obs,
    const float* __restrict__ g1, const float* __restrict__ b1,
    const f16* __restrict__ WTc,
    const float* __restrict__ g2, const float* __restrict__ b2,
    const float* __restrict__ g3, const float* __restrict__ b3,
    float* __restrict__ outF) {
  __shared__ __align__(16) char smem[138752];
  f16* sX = (f16*)smem;                        // [64][XS] activations (A operand)
  f16* sH = (f16*)(smem + 66560);              // [512][HS] h1 transposed (col-major)
  float2* sPart = (float2*)(smem + 134144);    // [512] per-wave LN partials
  float2* sStat = (float2*)(smem + 138240);    // [64] (mean, inv) per row

  int t = threadIdx.x, lane = t & 63, wv = t >> 6;
  int row16 = lane & 15, quad = lane >> 4;
  int rBase = blockIdx.x * 64;

  // per-lane bases
  const f16* sXb = sX + row16 * XS + quad * 8;                 // A fragment base
  // B fragment base: chunk-tiled. Wave's cols wv*64.., lane covers
  // row16*64B + quad*16B of the contiguous [16 rows][32 f16] = 1 KB segment.
  const f16* bw = WTc + wv * 2048 + row16 * 32 + quad * 8;

  f32x4 acc[4][4];
  f16x8 bfA[4], bfB[4];

  // preload GEMM1 chunk 0 B-fragments (arrive during the LN1 prologue)
  #pragma unroll
  for (int i = 0; i < 4; ++i) bfA[i] = *(const f16x8*)(bw + i * 512);

  // ---- LN1 prologue: each wave normalizes its 8 rows of Obs into sX ----
  {
    float4 w0 = *(const float4*)(g1 + lane * 4);
    float4 u0 = *(const float4*)(b1 + lane * 4);
    float4 w1 = *(const float4*)(g1 + 256 + lane * 4);
    float4 u1 = *(const float4*)(b1 + 256 + lane * 4);
    #pragma unroll
    for (int p = 0; p < 8; ++p) {
      int row = wv * 8 + p;
      const float* x = Obs + (((size_t)(rBase + row)) << 9);
      float4 v0 = *(const float4*)(x + lane * 4);
      float4 v1 = *(const float4*)(x + 256 + lane * 4);
      float s = v0.x + v0.y + v0.z + v0.w + v1.x + v1.y + v1.z + v1.w;
      float q = v0.x*v0.x + v0.y*v0.y + v0.z*v0.z + v0.w*v0.w
              + v1.x*v1.x + v1.y*v1.y + v1.z*v1.z + v1.w*v1.w;
      #pragma unroll
      for (int off = 1; off < 64; off <<= 1) {
        s += __shfl_xor(s, off, 64);
        q += __shfl_xor(q, off, 64);
      }
      float mean = s * (1.f / 512.f);
      float var  = q * (1.f / 512.f) - mean * mean;
      float inv  = 1.f / sqrtf(var + 1e-5f);
      f16x4 o0, o1;
      o0[0] = (f16)((v0.x - mean) * inv * w0.x + u0.x);
      o0[1] = (f16)((v0.y - mean) * inv * w0.y + u0.y);
      o0[2] = (f16)((v0.z - mean) * inv * w0.z + u0.z);
      o0[3] = (f16)((v0.w - mean) * inv * w0.w + u0.w);
      o1[0] = (f16)((v1.x - mean) * inv * w1.x + u1.x);
      o1[1] = (f16)((v1.y - mean) * inv * w1.y + u1.y);
      o1[2] = (f16)((v1.z - mean) * inv * w1.z + u1.z);
      o1[3] = (f16)((v1.w - mean) * inv * w1.w + u1.w);
      *(f16x4*)&sX[row * XS + lane * 4] = o0;
      *(f16x4*)&sX[row * XS + 256 + lane * 4] = o1;
    }
  }
  __syncthreads();   // sX (A1) ready for all waves

  for (int g = 0; g < 3; ++g) {
    #pragma unroll
    for (int mi = 0; mi < 4; ++mi)
      #pragma unroll
      for (int ni = 0; ni < 4; ++ni)
        acc[mi][ni] = (f32x4){0.f, 0.f, 0.f, 0.f};

    // K-loop: barrier-free, bf register-double-buffered (bfA preloaded c=0).
    // chunk c's 32-f16 K-slice of this wave's 64 B-rows is at bw + c*16384.
    #pragma unroll
    for (int c = 0; c < 16; c += 2) {
      #pragma unroll
      for (int i = 0; i < 4; ++i)
        bfB[i] = *(const f16x8*)(bw + (c + 1) * 16384 + i * 512);
      gemm_step(acc, sXb, bfA, c);
      if (c + 2 < 16) {
        #pragma unroll
        for (int i = 0; i < 4; ++i)
          bfA[i] = *(const f16x8*)(bw + (c + 2) * 16384 + i * 512);
      }
      gemm_step(acc, sXb, bfB, c + 1);
    }

    if (g == 2) {
      __syncthreads();   // all waves done reading sX -> safe to overlay sE
      float* sE = (float*)smem;
      #pragma unroll
      for (int half = 0; half < 2; ++half) {
        #pragma unroll
        for (int mi = 0; mi < 2; ++mi) {
          int rt = half * 2 + mi;
          #pragma unroll
          for (int ni = 0; ni < 4; ++ni) {
            int col = wv * 64 + ni * 16 + row16;
            #pragma unroll
            for (int rg = 0; rg < 4; ++rg)
              sE[(mi * 16 + quad * 4 + rg) * EPS32 + col] = acc[rt][ni][rg];
          }
        }
        __syncthreads();
        #pragma unroll
        for (int i = 0; i < 8; ++i) {
          int gi = t + i * 512;
          int row = gi >> 7, cg = (gi & 127) * 4;
          f32x4 v = *(const f32x4*)&sE[row * EPS32 + cg];
          *(f32x4*)&outF[(((size_t)(rBase + half * 32 + row)) << 9) + cg] = v;
        }
        __syncthreads();
      }
    } else {
      // tanh
      #pragma unroll
      for (int mi = 0; mi < 4; ++mi)
        #pragma unroll
        for (int ni = 0; ni < 4; ++ni)
          #pragma unroll
          for (int rg = 0; rg < 4; ++rg)
            acc[mi][ni][rg] = fast_tanh(acc[mi][ni][rg]);

      if (g == 0) {
        // stash h1 in LDS, transposed [col][row]: writer lane == reader lane
        // (same wv/row16/quad mapping on both sides) -> no barrier needed.
        #pragma unroll
        for (int mi = 0; mi < 4; ++mi)
          #pragma unroll
          for (int ni = 0; ni < 4; ++ni) {
            int col = wv * 64 + ni * 16 + row16;
            f16x4 h;
            #pragma unroll
            for (int rg = 0; rg < 4; ++rg) h[rg] = (f16)acc[mi][ni][rg];
            *(f16x4*)&sH[col * HS + mi * 16 + quad * 4] = h;
          }
      } else {
        // residual: h2 + h1 (read back own lane's stash)
        #pragma unroll
        for (int mi = 0; mi < 4; ++mi)
          #pragma unroll
          for (int ni = 0; ni < 4; ++ni) {
            int col = wv * 64 + ni * 16 + row16;
            f16x4 h = *(const f16x4*)&sH[col * HS + mi * 16 + quad * 4];
            #pragma unroll
            for (int rg = 0; rg < 4; ++rg)
              acc[mi][ni][rg] += (float)h[rg];
          }
      }

      const float* gp = (g == 0) ? g2 : g3;
      const float* bp = (g == 0) ? b2 : b3;
      float gva[4], bva[4];
      #pragma unroll
      for (int ni = 0; ni < 4; ++ni) {
        int col = wv * 64 + ni * 16 + row16;
        gva[ni] = gp[col]; bva[ni] = bp[col];
      }

      // per-row LN stats: lane partial over ni, butterfly over 16-lane groups
      #pragma unroll
      for (int mi = 0; mi < 4; ++mi)
        #pragma unroll
        for (int rg = 0; rg < 4; ++rg) {
          float s = 0.f, q = 0.f;
          #pragma unroll
          for (int ni = 0; ni < 4; ++ni) {
            float v = acc[mi][ni][rg];
            s += v; q += v * v;
          }
          #pragma unroll
          for (int off = 1; off < 16; off <<= 1) {
            s += __shfl_xor(s, off, 16);
            q += __shfl_xor(q, off, 16);
          }
          if (row16 == 0)
            sPart[wv * 64 + mi * 16 + quad * 4 + rg] = make_float2(s, q);
        }
      __syncthreads();   // sPart ready; also: all waves done reading sX
      if (t < 64) {
        float s = 0.f, q = 0.f;
        #pragma unroll
        for (int w = 0; w < 8; ++w) {
          float2 p = sPart[w * 64 + t];
          s += p.x; q += p.y;
        }
        float mean = s * (1.f / 512.f);
        float var  = q * (1.f / 512.f) - mean * mean;
        sStat[t] = make_float2(mean, 1.f / sqrtf(var + 1e-5f));
      }

      // preload next GEMM's chunk-0 B-fragments (covers L2 latency under LN)
      bw += 262144;
      #pragma unroll
      for (int i = 0; i < 4; ++i) bfA[i] = *(const f16x8*)(bw + i * 512);

      __syncthreads();   // sStat ready

      // normalize -> write next A operand back into sX (in place)
      #pragma unroll
      for (int mi = 0; mi < 4; ++mi)
        #pragma unroll
        for (int rg = 0; rg < 4; ++rg) {
          int row = mi * 16 + quad * 4 + rg;
          float2 st = sStat[row];
          #pragma unroll
          for (int ni = 0; ni < 4; ++ni) {
            int col = wv * 64 + ni * 16 + row16;
            sX[row * XS + col] = (f16)((acc[mi][ni][rg] - st.x) * st.y * gva[ni] + bva[ni]);
          }
        }
      __syncthreads();   // sX ready for next GEMM
    }
  }
}

// ---- Masked softmax over N: register-resident. Block = (b, 64-o chunk). ----
// Thread (c4 = t&15, nh = t>>4) owns cols oc*64 + c4*4..+3, rows n = nh+16j.
// Single exp: p = exp(v-m) kept in regs, reused for sum and the final scale.
__global__ __launch_bounds__(256, 2) void softmax_kernel(const float* __restrict__ o3,
                                                         const int* __restrict__ mask,
                                                         float* __restrict__ out) {
  __shared__ float4 smx[16][16];   // [nh][c4] partial col-maxes
  __shared__ float4 sms[16][16];   // [nh][c4] partial col-sums
  __shared__ int    smask[NN];

  int b  = blockIdx.x >> 3;
  int oc = blockIdx.x & 7;
  int t  = threadIdx.x;
  int c4 = t & 15;
  int nh = t >> 4;

  const float4* src = (const float4*)(o3 + (((size_t)(b * NN)) << 9)) + oc * 16 + c4;
  float4 v[16];
  #pragma unroll
  for (int j = 0; j < 16; ++j)
    v[j] = src[(size_t)(nh + 16 * j) * 128];

  int mt = mask[b * NN + t];
  int any = __syncthreads_or(mt);
  smask[t] = (t == 0 && !any) ? 1 : mt;
  __syncthreads();

  const float NEG = -3.4e38f;
  #pragma unroll
  for (int j = 0; j < 16; ++j)
    if (!smask[nh + 16 * j]) v[j] = (float4){NEG, NEG, NEG, NEG};

  // col max over this thread's 16 rows, then over the 16 nh groups via LDS
  float4 m4 = v[0];
  #pragma unroll
  for (int j = 1; j < 16; ++j) {
    m4.x = fmaxf(m4.x, v[j].x); m4.y = fmaxf(m4.y, v[j].y);
    m4.z = fmaxf(m4.z, v[j].z); m4.w = fmaxf(m4.w, v[j].w);
  }
  smx[nh][c4] = m4;
  __syncthreads();
  float4 mm = smx[0][c4];
  #pragma unroll
  for (int k = 1; k < 16; ++k) {
    float4 o = smx[k][c4];
    mm.x = fmaxf(mm.x, o.x); mm.y = fmaxf(mm.y, o.y);
    mm.z = fmaxf(mm.z, o.z); mm.w = fmaxf(mm.w, o.w);
  }

  // p = exp(v - m) in-register (single exp), col sum
  float4 s4 = {0.f, 0.f, 0.f, 0.f};
  #pragma unroll
  for (int j = 0; j < 16; ++j) {
    v[j].x = __expf(v[j].x - mm.x); s4.x += v[j].x;
    v[j].y = __expf(v[j].y - mm.y); s4.y += v[j].y;
    v[j].z = __expf(v[j].z - mm.z); s4.z += v[j].z;
    v[j].w = __expf(v[j].w - mm.w); s4.w += v[j].w;
  }
  sms[nh][c4] = s4;
  __syncthreads();
  float4 tot = sms[0][c4];
  #pragma unroll
  for (int k = 1; k < 16; ++k) {
    float4 o = sms[k][c4];
    tot.x += o.x; tot.y += o.y; tot.z += o.z; tot.w += o.w;
  }
  float4 inv = {1.f / tot.x, 1.f / tot.y, 1.f / tot.z, 1.f / tot.w};

  float4* dst = (float4*)(out + (((size_t)(b * NN)) << 9)) + oc * 16 + c4;
  #pragma unroll
  for (int j = 0; j < 16; ++j) {
    float4 r;
    r.x = v[j].x * inv.x;
    r.y = v[j].y * inv.y;
    r.z = v[j].z * inv.z;
    r.w = v[j].w * inv.w;
    dst[(size_t)(nh + 16 * j) * 128] = r;
  }
}

extern "C" void kernel_launch(void* const* d_in, const int* in_sizes, int n_in,
                              void* d_out, int out_size, void* d_ws, size_t ws_size,
                              hipStream_t stream) {
  const float* Obs = (const float*)d_in[0];
  const int*   msk = (const int*)d_in[1];
  const float* g1  = (const float*)d_in[2];
  const float* b1  = (const float*)d_in[3];
  const float* W1  = (const float*)d_in[4];
  const float* g2  = (const float*)d_in[5];
  const float* b2  = (const float*)d_in[6];
  const float* W2  = (const float*)d_in[7];
  const float* g3  = (const float*)d_in[8];
  const float* b3  = (const float*)d_in[9];
  const float* W3  = (const float*)d_in[10];
  float* out = (float*)d_out;

  char* ws = (char*)d_ws;
  const size_t MB = 1u << 20;
  float* Lg = (float*)ws;                  // [0, 64M) logits fp32
  f16*   WTc = (f16*)(ws + 64 * MB);       // 1.5 MB chunk-tiled

  prep_w_kernel<<<3072, 256, 0, stream>>>(W1, W2, W3, WTc);
  mega_kernel<<<512, 512, 0, stream>>>(Obs, g1, b1, WTc, g2, b2, g3, b3, Lg);
  softmax_kernel<<<1024, 256, 0, stream>>>(Lg, msk, out);
}

// Round 10
// 270.941 us; speedup vs baseline: 1.0556x; 1.0119x over previous
//
#include <hip/hip_runtime.h>

// B=128, N=256, D=O=512. R = B*N = 32768 rows.
// Pipeline (3 kernels):
//   prep_w:  W -> chunk-tiled W^T f16: WTc[g][c][o][32], c = K-chunk of 32.
//   mega:    per 32-row slab: LN1(Obs)->sX, then {GEMM1+tanh -> h1(regs) ->
//            LN2 -> sX, GEMM2+tanh+h1 -> LN3 -> sX, GEMM3 -> logits fp32}.
//   softmax: masked softmax over N, register-resident, single-exp.
// SHAPE CHANGE (round 10): 32-row slabs, 1024 blocks. 8 waves x (32r x 64c)
// -> acc[2][4] = 32 unified regs (VGPR_Count evidence across rounds 4-9 says
// the reported 128 is the UNIFIED total incl. accumulator: acc[4][4] builds
// all report 128 and spill; the lone acc[2][4] build reported 64). Live set
// acc32+bf32+af8+h1s16+addr~25 = ~115 < 128 -> no spills, h1 in registers.
// LDS ~36 KB (vs 71-139) -> 2-3 blocks/CU co-resident (every 64-row variant
// pinned at 1 block / 22% occupancy): cross-block overlap finally hides LN
// phases and L2 latency. Cost: B L2 traffic doubles to 1.5 GB (~43us floor)
// -- we are at 16% HBM / far from L2 BW, so latency cover wins.
// K-loop: barrier-free, B direct from L2-hot chunk-tiled WTc (coalesced 1 KB
// per wave-instr), register double-buffered dist-1. A in LDS, XS=520.

#define NN 256

typedef _Float16 f16;
typedef __attribute__((ext_vector_type(4))) _Float16 f16x4;
typedef __attribute__((ext_vector_type(8))) _Float16 f16x8;
typedef __attribute__((ext_vector_type(4))) float f32x4;

#define XS    520   // sX row stride (f16)
#define EPS32 516   // f32 logits epilogue stride

__device__ __forceinline__ float fast_tanh(float x) {
  float e = __expf(2.f * x);
  return 1.f - 2.f * __builtin_amdgcn_rcpf(e + 1.f);
}

// ---- W[d][o] fp32 -> WTc[g][c][o][dlow] f16 (chunk-tiled transpose) ----
__global__ void prep_w_kernel(const float* __restrict__ W1, const float* __restrict__ W2,
                              const float* __restrict__ W3, f16* __restrict__ WTc) {
  int idx = blockIdx.x * 256 + threadIdx.x;
  int g    = idx >> 18;
  int rem  = idx & 0x3FFFF;
  int c    = rem >> 14;          // K-chunk (16 of them)
  int o    = (rem >> 5) & 511;   // output col
  int dlow = rem & 31;           // k within chunk
  const float* W = (g == 0) ? W1 : (g == 1) ? W2 : W3;
  WTc[idx] = (f16)W[(c * 32 + dlow) * 512 + o];
}

// one K-step: 2 ds_read_b128 of A fragments + 8 MFMA against preloaded bf
__device__ __forceinline__ void gemm_step(f32x4 acc[2][4], const f16* __restrict__ sXb,
                                          const f16x8 bf[4], int c) {
  f16x8 af[2];
  #pragma unroll
  for (int i = 0; i < 2; ++i)
    af[i] = *(const f16x8*)&sXb[i * 16 * XS + c * 32];
  #pragma unroll
  for (int mi = 0; mi < 2; ++mi)
    #pragma unroll
    for (int ni = 0; ni < 4; ++ni)
      acc[mi][ni] = __builtin_amdgcn_mfma_f32_16x16x32_f16(af[mi], bf[ni], acc[mi][ni], 0, 0, 0);
}

// ---- Mega kernel: LN1 + 3 GEMMs + 2 LNs + tanh + residual, one 32-row slab ----
__global__ __launch_bounds__(512) void mega_kernel(
    const float* __restrict__ Obs,
    const float* __restrict__ g1, const float* __restrict__ b1,
    const f16* __restrict__ WTc,
    const float* __restrict__ g2, const float* __restrict__ b2,
    const float* __restrict__ g3, const float* __restrict__ b3,
    float* __restrict__ outF) {
  __shared__ __align__(16) char smem[35840];
  f16* sX = (f16*)smem;                        // [32][XS] activations (A operand)
  float2* sPart = (float2*)(smem + 33280);     // [256] = [8 waves][32 rows] LN partials
  float2* sStat = (float2*)(smem + 35328);     // [32] (mean, inv) per row

  int t = threadIdx.x, lane = t & 63, wv = t >> 6;
  int row16 = lane & 15, quad = lane >> 4;
  int rBase = blockIdx.x * 32;

  // per-lane bases
  const f16* sXb = sX + row16 * XS + quad * 8;                 // A fragment base
  // B fragment base: chunk-tiled. Wave's cols wv*64.., lane covers
  // row16*64B + quad*16B of the contiguous [16 rows][32 f16] = 1 KB segment.
  const f16* bw = WTc + wv * 2048 + row16 * 32 + quad * 8;

  f32x4 acc[2][4];
  f16x8 bfA[4], bfB[4];
  f16x4 h1s[2][4];   // residual tanh(A1@W1), register-resident across GEMM2

  // preload GEMM1 chunk 0 B-fragments (arrive during the LN1 prologue)
  #pragma unroll
  for (int i = 0; i < 4; ++i) bfA[i] = *(const f16x8*)(bw + i * 512);

  // ---- LN1 prologue: each wave normalizes its 4 rows of Obs into sX ----
  {
    float4 w0 = *(const float4*)(g1 + lane * 4);
    float4 u0 = *(const float4*)(b1 + lane * 4);
    float4 w1 = *(const float4*)(g1 + 256 + lane * 4);
    float4 u1 = *(const float4*)(b1 + 256 + lane * 4);
    #pragma unroll
    for (int p = 0; p < 4; ++p) {
      int row = wv * 4 + p;
      const float* x = Obs + (((size_t)(rBase + row)) << 9);
      float4 v0 = *(const float4*)(x + lane * 4);
      float4 v1 = *(const float4*)(x + 256 + lane * 4);
      float s = v0.x + v0.y + v0.z + v0.w + v1.x + v1.y + v1.z + v1.w;
      float q = v0.x*v0.x + v0.y*v0.y + v0.z*v0.z + v0.w*v0.w
              + v1.x*v1.x + v1.y*v1.y + v1.z*v1.z + v1.w*v1.w;
      #pragma unroll
      for (int off = 1; off < 64; off <<= 1) {
        s += __shfl_xor(s, off, 64);
        q += __shfl_xor(q, off, 64);
      }
      float mean = s * (1.f / 512.f);
      float var  = q * (1.f / 512.f) - mean * mean;
      float inv  = 1.f / sqrtf(var + 1e-5f);
      f16x4 o0, o1;
      o0[0] = (f16)((v0.x - mean) * inv * w0.x + u0.x);
      o0[1] = (f16)((v0.y - mean) * inv * w0.y + u0.y);
      o0[2] = (f16)((v0.z - mean) * inv * w0.z + u0.z);
      o0[3] = (f16)((v0.w - mean) * inv * w0.w + u0.w);
      o1[0] = (f16)((v1.x - mean) * inv * w1.x + u1.x);
      o1[1] = (f16)((v1.y - mean) * inv * w1.y + u1.y);
      o1[2] = (f16)((v1.z - mean) * inv * w1.z + u1.z);
      o1[3] = (f16)((v1.w - mean) * inv * w1.w + u1.w);
      *(f16x4*)&sX[row * XS + lane * 4] = o0;
      *(f16x4*)&sX[row * XS + 256 + lane * 4] = o1;
    }
  }
  __syncthreads();   // sX (A1) ready for all waves

  for (int g = 0; g < 3; ++g) {
    #pragma unroll
    for (int mi = 0; mi < 2; ++mi)
      #pragma unroll
      for (int ni = 0; ni < 4; ++ni)
        acc[mi][ni] = (f32x4){0.f, 0.f, 0.f, 0.f};

    // K-loop: barrier-free, bf register-double-buffered (bfA preloaded c=0).
    // chunk c's 32-f16 K-slice of this wave's 64 B-rows is at bw + c*16384.
    #pragma unroll
    for (int c = 0; c < 16; c += 2) {
      #pragma unroll
      for (int i = 0; i < 4; ++i)
        bfB[i] = *(const f16x8*)(bw + (c + 1) * 16384 + i * 512);
      gemm_step(acc, sXb, bfA, c);
      if (c + 2 < 16) {
        #pragma unroll
        for (int i = 0; i < 4; ++i)
          bfA[i] = *(const f16x8*)(bw + (c + 2) * 16384 + i * 512);
      }
      gemm_step(acc, sXb, bfB, c + 1);
    }

    if (g == 2) {
      __syncthreads();   // all waves done reading sX -> safe to overlay sE
      float* sE = (float*)smem;   // [16][EPS32] f32, one 16-row half at a time
      #pragma unroll
      for (int half = 0; half < 2; ++half) {
        #pragma unroll
        for (int ni = 0; ni < 4; ++ni) {
          int col = wv * 64 + ni * 16 + row16;
          #pragma unroll
          for (int rg = 0; rg < 4; ++rg)
            sE[(quad * 4 + rg) * EPS32 + col] = acc[half][ni][rg];
        }
        __syncthreads();
        #pragma unroll
        for (int i = 0; i < 4; ++i) {
          int gi = t + i * 512;
          int row = gi >> 7, cg = (gi & 127) * 4;
          f32x4 v = *(const f32x4*)&sE[row * EPS32 + cg];
          *(f32x4*)&outF[(((size_t)(rBase + half * 16 + row)) << 9) + cg] = v;
        }
        __syncthreads();
      }
    } else {
      // tanh
      #pragma unroll
      for (int mi = 0; mi < 2; ++mi)
        #pragma unroll
        for (int ni = 0; ni < 4; ++ni)
          #pragma unroll
          for (int rg = 0; rg < 4; ++rg)
            acc[mi][ni][rg] = fast_tanh(acc[mi][ni][rg]);

      if (g == 0) {
        // stash h1 (same (row,col) mapping as GEMM2's acc)
        #pragma unroll
        for (int mi = 0; mi < 2; ++mi)
          #pragma unroll
          for (int ni = 0; ni < 4; ++ni) {
            f16x4 h;
            #pragma unroll
            for (int rg = 0; rg < 4; ++rg) h[rg] = (f16)acc[mi][ni][rg];
            h1s[mi][ni] = h;
          }
      } else {
        // residual: h2 + h1
        #pragma unroll
        for (int mi = 0; mi < 2; ++mi)
          #pragma unroll
          for (int ni = 0; ni < 4; ++ni)
            #pragma unroll
            for (int rg = 0; rg < 4; ++rg)
              acc[mi][ni][rg] += (float)h1s[mi][ni][rg];
      }

      const float* gp = (g == 0) ? g2 : g3;
      const float* bp = (g == 0) ? b2 : b3;
      float gva[4], bva[4];
      #pragma unroll
      for (int ni = 0; ni < 4; ++ni) {
        int col = wv * 64 + ni * 16 + row16;
        gva[ni] = gp[col]; bva[ni] = bp[col];
      }

      // per-row LN stats: lane partial over ni, butterfly over 16-lane groups
      #pragma unroll
      for (int mi = 0; mi < 2; ++mi)
        #pragma unroll
        for (int rg = 0; rg < 4; ++rg) {
          float s = 0.f, q = 0.f;
          #pragma unroll
          for (int ni = 0; ni < 4; ++ni) {
            float v = acc[mi][ni][rg];
            s += v; q += v * v;
          }
          #pragma unroll
          for (int off = 1; off < 16; off <<= 1) {
            s += __shfl_xor(s, off, 16);
            q += __shfl_xor(q, off, 16);
          }
          if (row16 == 0)
            sPart[wv * 32 + mi * 16 + quad * 4 + rg] = make_float2(s, q);
        }
      __syncthreads();   // sPart ready; also: all waves done reading sX
      if (t < 32) {
        float s = 0.f, q = 0.f;
        #pragma unroll
        for (int w = 0; w < 8; ++w) {
          float2 p = sPart[w * 32 + t];
          s += p.x; q += p.y;
        }
        float mean = s * (1.f / 512.f);
        float var  = q * (1.f / 512.f) - mean * mean;
        sStat[t] = make_float2(mean, 1.f / sqrtf(var + 1e-5f));
      }

      // preload next GEMM's chunk-0 B-fragments (covers L2 latency under LN)
      bw += 262144;
      #pragma unroll
      for (int i = 0; i < 4; ++i) bfA[i] = *(const f16x8*)(bw + i * 512);

      __syncthreads();   // sStat ready

      // normalize -> write next A operand back into sX (in place)
      #pragma unroll
      for (int mi = 0; mi < 2; ++mi)
        #pragma unroll
        for (int rg = 0; rg < 4; ++rg) {
          int row = mi * 16 + quad * 4 + rg;
          float2 st = sStat[row];
          #pragma unroll
          for (int ni = 0; ni < 4; ++ni) {
            int col = wv * 64 + ni * 16 + row16;
            sX[row * XS + col] = (f16)((acc[mi][ni][rg] - st.x) * st.y * gva[ni] + bva[ni]);
          }
        }
      __syncthreads();   // sX ready for next GEMM
    }
  }
}

// ---- Masked softmax over N: register-resident. Block = (b, 64-o chunk). ----
// Thread (c4 = t&15, nh = t>>4) owns cols oc*64 + c4*4..+3, rows n = nh+16j.
// Single exp: p = exp(v-m) kept in regs, reused for sum and the final scale.
__global__ __launch_bounds__(256, 2) void softmax_kernel(const float* __restrict__ o3,
                                                         const int* __restrict__ mask,
                                                         float* __restrict__ out) {
  __shared__ float4 smx[16][16];   // [nh][c4] partial col-maxes
  __shared__ float4 sms[16][16];   // [nh][c4] partial col-sums
  __shared__ int    smask[NN];

  int b  = blockIdx.x >> 3;
  int oc = blockIdx.x & 7;
  int t  = threadIdx.x;
  int c4 = t & 15;
  int nh = t >> 4;

  const float4* src = (const float4*)(o3 + (((size_t)(b * NN)) << 9)) + oc * 16 + c4;
  float4 v[16];
  #pragma unroll
  for (int j = 0; j < 16; ++j)
    v[j] = src[(size_t)(nh + 16 * j) * 128];

  int mt = mask[b * NN + t];
  int any = __syncthreads_or(mt);
  smask[t] = (t == 0 && !any) ? 1 : mt;
  __syncthreads();

  const float NEG = -3.4e38f;
  #pragma unroll
  for (int j = 0; j < 16; ++j)
    if (!smask[nh + 16 * j]) v[j] = (float4){NEG, NEG, NEG, NEG};

  // col max over this thread's 16 rows, then over the 16 nh groups via LDS
  float4 m4 = v[0];
  #pragma unroll
  for (int j = 1; j < 16; ++j) {
    m4.x = fmaxf(m4.x, v[j].x); m4.y = fmaxf(m4.y, v[j].y);
    m4.z = fmaxf(m4.z, v[j].z); m4.w = fmaxf(m4.w, v[j].w);
  }
  smx[nh][c4] = m4;
  __syncthreads();
  float4 mm = smx[0][c4];
  #pragma unroll
  for (int k = 1; k < 16; ++k) {
    float4 o = smx[k][c4];
    mm.x = fmaxf(mm.x, o.x); mm.y = fmaxf(mm.y, o.y);
    mm.z = fmaxf(mm.z, o.z); mm.w = fmaxf(mm.w, o.w);
  }

  // p = exp(v - m) in-register (single exp), col sum
  float4 s4 = {0.f, 0.f, 0.f, 0.f};
  #pragma unroll
  for (int j = 0; j < 16; ++j) {
    v[j].x = __expf(v[j].x - mm.x); s4.x += v[j].x;
    v[j].y = __expf(v[j].y - mm.y); s4.y += v[j].y;
    v[j].z = __expf(v[j].z - mm.z); s4.z += v[j].z;
    v[j].w = __expf(v[j].w - mm.w); s4.w += v[j].w;
  }
  sms[nh][c4] = s4;
  __syncthreads();
  float4 tot = sms[0][c4];
  #pragma unroll
  for (int k = 1; k < 16; ++k) {
    float4 o = sms[k][c4];
    tot.x += o.x; tot.y += o.y; tot.z += o.z; tot.w += o.w;
  }
  float4 inv = {1.f / tot.x, 1.f / tot.y, 1.f / tot.z, 1.f / tot.w};

  float4* dst = (float4*)(out + (((size_t)(b * NN)) << 9)) + oc * 16 + c4;
  #pragma unroll
  for (int j = 0; j < 16; ++j) {
    float4 r;
    r.x = v[j].x * inv.x;
    r.y = v[j].y * inv.y;
    r.z = v[j].z * inv.z;
    r.w = v[j].w * inv.w;
    dst[(size_t)(nh + 16 * j) * 128] = r;
  }
}

extern "C" void kernel_launch(void* const* d_in, const int* in_sizes, int n_in,
                              void* d_out, int out_size, void* d_ws, size_t ws_size,
                              hipStream_t stream) {
  const float* Obs = (const float*)d_in[0];
  const int*   msk = (const int*)d_in[1];
  const float* g1  = (const float*)d_in[2];
  const float* b1  = (const float*)d_in[3];
  const float* W1  = (const float*)d_in[4];
  const float* g2  = (const float*)d_in[5];
  const float* b2  = (const float*)d_in[6];
  const float* W2  = (const float*)d_in[7];
  const float* g3  = (const float*)d_in[8];
  const float* b3  = (const float*)d_in[9];
  const float* W3  = (const float*)d_in[10];
  float* out = (float*)d_out;

  char* ws = (char*)d_ws;
  const size_t MB = 1u << 20;
  float* Lg = (float*)ws;                  // [0, 64M) logits fp32
  f16*   WTc = (f16*)(ws + 64 * MB);       // 1.5 MB chunk-tiled

  prep_w_kernel<<<3072, 256, 0, stream>>>(W1, W2, W3, WTc);
  mega_kernel<<<1024, 512, 0, stream>>>(Obs, g1, b1, WTc, g2, b2, g3, b3, Lg);
  softmax_kernel<<<1024, 256, 0, stream>>>(Lg, msk, out);
}

// Round 11
// 270.324 us; speedup vs baseline: 1.0581x; 1.0023x over previous
//
#include <hip/hip_runtime.h>

// B=128, N=256, D=O=512. R = B*N = 32768 rows.
// Pipeline (3 kernels):
//   prep_w:  W -> chunk-tiled W^T f16: WTc[g][c][o][32], c = K-chunk of 32.
//   mega:    per 32-row slab: LN1(Obs)->sX, then {GEMM1+tanh -> h1(regs) ->
//            LN2 -> sX, GEMM2+tanh+h1 -> LN3 -> sX, GEMM3 -> logits fp32}.
//   softmax: masked softmax over N, register-resident, 2048-block TLP.
// Round 11: (1) K-chunk ROTATION rot=blockIdx&15 in mega. Round-10 closed
// the spill thread (WRITE=64MB exactly, VGPR 96) yet time stayed ~155us with
// MfmaUtil 13.7% / HBM 9.5% -- every pipe idle. Remaining theory: all 1024
// blocks stream the SAME 512 KB WTc in the SAME order -> lockstep same-line
// requests serialize on the same L2 banks (hot-line contention), which is
// also why ~50us/GEMM was invariant across every B-path variant. Rotation
// decorrelates block streams across 16 positions (MFMA accum is order-
// independent; rot pattern verified correct in round 5's passing run).
// (2) softmax: 2048 blocks x 256 thr, 8 rows/thread (v[8], ~60 regs) ->
// ~8 blocks/CU latency cover. Non-mega time is ~110us by subtraction;
// if softmax was the sink, total drops accordingly.

#define NN 256

typedef _Float16 f16;
typedef __attribute__((ext_vector_type(4))) _Float16 f16x4;
typedef __attribute__((ext_vector_type(8))) _Float16 f16x8;
typedef __attribute__((ext_vector_type(4))) float f32x4;

#define XS    520   // sX row stride (f16)
#define EPS32 516   // f32 logits epilogue stride

__device__ __forceinline__ float fast_tanh(float x) {
  float e = __expf(2.f * x);
  return 1.f - 2.f * __builtin_amdgcn_rcpf(e + 1.f);
}

// ---- W[d][o] fp32 -> WTc[g][c][o][dlow] f16 (chunk-tiled transpose) ----
__global__ void prep_w_kernel(const float* __restrict__ W1, const float* __restrict__ W2,
                              const float* __restrict__ W3, f16* __restrict__ WTc) {
  int idx = blockIdx.x * 256 + threadIdx.x;
  int g    = idx >> 18;
  int rem  = idx & 0x3FFFF;
  int c    = rem >> 14;          // K-chunk (16 of them)
  int o    = (rem >> 5) & 511;   // output col
  int dlow = rem & 31;           // k within chunk
  const float* W = (g == 0) ? W1 : (g == 1) ? W2 : W3;
  WTc[idx] = (f16)W[(c * 32 + dlow) * 512 + o];
}

// one K-step: 2 ds_read_b128 of A fragments + 8 MFMA against preloaded bf
__device__ __forceinline__ void gemm_step(f32x4 acc[2][4], const f16* __restrict__ sXb,
                                          const f16x8 bf[4], int c) {
  f16x8 af[2];
  #pragma unroll
  for (int i = 0; i < 2; ++i)
    af[i] = *(const f16x8*)&sXb[i * 16 * XS + c * 32];
  #pragma unroll
  for (int mi = 0; mi < 2; ++mi)
    #pragma unroll
    for (int ni = 0; ni < 4; ++ni)
      acc[mi][ni] = __builtin_amdgcn_mfma_f32_16x16x32_f16(af[mi], bf[ni], acc[mi][ni], 0, 0, 0);
}

// ---- Mega kernel: LN1 + 3 GEMMs + 2 LNs + tanh + residual, one 32-row slab ----
__global__ __launch_bounds__(512) void mega_kernel(
    const float* __restrict__ Obs,
    const float* __restrict__ g1, const float* __restrict__ b1,
    const f16* __restrict__ WTc,
    const float* __restrict__ g2, const float* __restrict__ b2,
    const float* __restrict__ g3, const float* __restrict__ b3,
    float* __restrict__ outF) {
  __shared__ __align__(16) char smem[35840];
  f16* sX = (f16*)smem;                        // [32][XS] activations (A operand)
  float2* sPart = (float2*)(smem + 33280);     // [256] = [8 waves][32 rows] LN partials
  float2* sStat = (float2*)(smem + 35328);     // [32] (mean, inv) per row

  int t = threadIdx.x, lane = t & 63, wv = t >> 6;
  int row16 = lane & 15, quad = lane >> 4;
  int rBase = blockIdx.x * 32;
  int rot = blockIdx.x & 15;                   // K-chunk rotation (decorrelate L2 streams)

  // per-lane bases
  const f16* sXb = sX + row16 * XS + quad * 8;                 // A fragment base
  // B fragment base: chunk-tiled. Wave's cols wv*64.., lane covers
  // row16*64B + quad*16B of the contiguous [16 rows][32 f16] = 1 KB segment.
  const f16* bw = WTc + wv * 2048 + row16 * 32 + quad * 8;

  f32x4 acc[2][4];
  f16x8 bfA[4], bfB[4];
  f16x4 h1s[2][4];   // residual tanh(A1@W1), register-resident across GEMM2

  // preload GEMM1 chunk `rot` B-fragments (arrive during the LN1 prologue)
  #pragma unroll
  for (int i = 0; i < 4; ++i) bfA[i] = *(const f16x8*)(bw + rot * 16384 + i * 512);

  // ---- LN1 prologue: each wave normalizes its 4 rows of Obs into sX ----
  {
    float4 w0 = *(const float4*)(g1 + lane * 4);
    float4 u0 = *(const float4*)(b1 + lane * 4);
    float4 w1 = *(const float4*)(g1 + 256 + lane * 4);
    float4 u1 = *(const float4*)(b1 + 256 + lane * 4);
    #pragma unroll
    for (int p = 0; p < 4; ++p) {
      int row = wv * 4 + p;
      const float* x = Obs + (((size_t)(rBase + row)) << 9);
      float4 v0 = *(const float4*)(x + lane * 4);
      float4 v1 = *(const float4*)(x + 256 + lane * 4);
      float s = v0.x + v0.y + v0.z + v0.w + v1.x + v1.y + v1.z + v1.w;
      float q = v0.x*v0.x + v0.y*v0.y + v0.z*v0.z + v0.w*v0.w
              + v1.x*v1.x + v1.y*v1.y + v1.z*v1.z + v1.w*v1.w;
      #pragma unroll
      for (int off = 1; off < 64; off <<= 1) {
        s += __shfl_xor(s, off, 64);
        q += __shfl_xor(q, off, 64);
      }
      float mean = s * (1.f / 512.f);
      float var  = q * (1.f / 512.f) - mean * mean;
      float inv  = 1.f / sqrtf(var + 1e-5f);
      f16x4 o0, o1;
      o0[0] = (f16)((v0.x - mean) * inv * w0.x + u0.x);
      o0[1] = (f16)((v0.y - mean) * inv * w0.y + u0.y);
      o0[2] = (f16)((v0.z - mean) * inv * w0.z + u0.z);
      o0[3] = (f16)((v0.w - mean) * inv * w0.w + u0.w);
      o1[0] = (f16)((v1.x - mean) * inv * w1.x + u1.x);
      o1[1] = (f16)((v1.y - mean) * inv * w1.y + u1.y);
      o1[2] = (f16)((v1.z - mean) * inv * w1.z + u1.z);
      o1[3] = (f16)((v1.w - mean) * inv * w1.w + u1.w);
      *(f16x4*)&sX[row * XS + lane * 4] = o0;
      *(f16x4*)&sX[row * XS + 256 + lane * 4] = o1;
    }
  }
  __syncthreads();   // sX (A1) ready for all waves

  for (int g = 0; g < 3; ++g) {
    #pragma unroll
    for (int mi = 0; mi < 2; ++mi)
      #pragma unroll
      for (int ni = 0; ni < 4; ++ni)
        acc[mi][ni] = (f32x4){0.f, 0.f, 0.f, 0.f};

    // K-loop: barrier-free, bf register-double-buffered, rotated chunk order.
    // Step consumes chunk (rot+i)&15; A-read and B-read use the same chunk id.
    #pragma unroll
    for (int i2 = 0; i2 < 16; i2 += 2) {
      int ca = (rot + i2) & 15;
      int cb = (rot + i2 + 1) & 15;
      #pragma unroll
      for (int i = 0; i < 4; ++i)
        bfB[i] = *(const f16x8*)(bw + cb * 16384 + i * 512);
      gemm_step(acc, sXb, bfA, ca);
      if (i2 + 2 < 16) {
        int cc = (rot + i2 + 2) & 15;
        #pragma unroll
        for (int i = 0; i < 4; ++i)
          bfA[i] = *(const f16x8*)(bw + cc * 16384 + i * 512);
      }
      gemm_step(acc, sXb, bfB, cb);
    }

    if (g == 2) {
      __syncthreads();   // all waves done reading sX -> safe to overlay sE
      float* sE = (float*)smem;   // [16][EPS32] f32, one 16-row half at a time
      #pragma unroll
      for (int half = 0; half < 2; ++half) {
        #pragma unroll
        for (int ni = 0; ni < 4; ++ni) {
          int col = wv * 64 + ni * 16 + row16;
          #pragma unroll
          for (int rg = 0; rg < 4; ++rg)
            sE[(quad * 4 + rg) * EPS32 + col] = acc[half][ni][rg];
        }
        __syncthreads();
        #pragma unroll
        for (int i = 0; i < 4; ++i) {
          int gi = t + i * 512;
          int row = gi >> 7, cg = (gi & 127) * 4;
          f32x4 v = *(const f32x4*)&sE[row * EPS32 + cg];
          *(f32x4*)&outF[(((size_t)(rBase + half * 16 + row)) << 9) + cg] = v;
        }
        __syncthreads();
      }
    } else {
      // tanh
      #pragma unroll
      for (int mi = 0; mi < 2; ++mi)
        #pragma unroll
        for (int ni = 0; ni < 4; ++ni)
          #pragma unroll
          for (int rg = 0; rg < 4; ++rg)
            acc[mi][ni][rg] = fast_tanh(acc[mi][ni][rg]);

      if (g == 0) {
        // stash h1 (same (row,col) mapping as GEMM2's acc)
        #pragma unroll
        for (int mi = 0; mi < 2; ++mi)
          #pragma unroll
          for (int ni = 0; ni < 4; ++ni) {
            f16x4 h;
            #pragma unroll
            for (int rg = 0; rg < 4; ++rg) h[rg] = (f16)acc[mi][ni][rg];
            h1s[mi][ni] = h;
          }
      } else {
        // residual: h2 + h1
        #pragma unroll
        for (int mi = 0; mi < 2; ++mi)
          #pragma unroll
          for (int ni = 0; ni < 4; ++ni)
            #pragma unroll
            for (int rg = 0; rg < 4; ++rg)
              acc[mi][ni][rg] += (float)h1s[mi][ni][rg];
      }

      const float* gp = (g == 0) ? g2 : g3;
      const float* bp = (g == 0) ? b2 : b3;
      float gva[4], bva[4];
      #pragma unroll
      for (int ni = 0; ni < 4; ++ni) {
        int col = wv * 64 + ni * 16 + row16;
        gva[ni] = gp[col]; bva[ni] = bp[col];
      }

      // per-row LN stats: lane partial over ni, butterfly over 16-lane groups
      #pragma unroll
      for (int mi = 0; mi < 2; ++mi)
        #pragma unroll
        for (int rg = 0; rg < 4; ++rg) {
          float s = 0.f, q = 0.f;
          #pragma unroll
          for (int ni = 0; ni < 4; ++ni) {
            float v = acc[mi][ni][rg];
            s += v; q += v * v;
          }
          #pragma unroll
          for (int off = 1; off < 16; off <<= 1) {
            s += __shfl_xor(s, off, 16);
            q += __shfl_xor(q, off, 16);
          }
          if (row16 == 0)
            sPart[wv * 32 + mi * 16 + quad * 4 + rg] = make_float2(s, q);
        }
      __syncthreads();   // sPart ready; also: all waves done reading sX
      if (t < 32) {
        float s = 0.f, q = 0.f;
        #pragma unroll
        for (int w = 0; w < 8; ++w) {
          float2 p = sPart[w * 32 + t];
          s += p.x; q += p.y;
        }
        float mean = s * (1.f / 512.f);
        float var  = q * (1.f / 512.f) - mean * mean;
        sStat[t] = make_float2(mean, 1.f / sqrtf(var + 1e-5f));
      }

      // preload next GEMM's chunk-`rot` B-fragments (covers L2 latency)
      bw += 262144;
      #pragma unroll
      for (int i = 0; i < 4; ++i) bfA[i] = *(const f16x8*)(bw + rot * 16384 + i * 512);

      __syncthreads();   // sStat ready

      // normalize -> write next A operand back into sX (in place)
      #pragma unroll
      for (int mi = 0; mi < 2; ++mi)
        #pragma unroll
        for (int rg = 0; rg < 4; ++rg) {
          int row = mi * 16 + quad * 4 + rg;
          float2 st = sStat[row];
          #pragma unroll
          for (int ni = 0; ni < 4; ++ni) {
            int col = wv * 64 + ni * 16 + row16;
            sX[row * XS + col] = (f16)((acc[mi][ni][rg] - st.x) * st.y * gva[ni] + bva[ni]);
          }
        }
      __syncthreads();   // sX ready for next GEMM
    }
  }
}

// ---- Masked softmax over N: register-resident, high-TLP. ----
// Block = (b, 32-col chunk): 2048 blocks. Thread (c8 = t&7, nh = t>>3) owns
// cols oc*32 + c8*4..+3, rows n = nh + 32j (j<8). v[8] = 32 data regs.
__global__ __launch_bounds__(256) void softmax_kernel(const float* __restrict__ o3,
                                                      const int* __restrict__ mask,
                                                      float* __restrict__ out) {
  __shared__ float4 smx[32][8];   // [nh][c8] partial col-maxes
  __shared__ float4 sms[32][8];   // [nh][c8] partial col-sums
  __shared__ int    smask[NN];

  int b  = blockIdx.x >> 4;
  int oc = blockIdx.x & 15;
  int t  = threadIdx.x;
  int c8 = t & 7;
  int nh = t >> 3;

  const float4* src = (const float4*)(o3 + (((size_t)(b * NN)) << 9)) + oc * 8 + c8;
  float4 v[8];
  #pragma unroll
  for (int j = 0; j < 8; ++j)
    v[j] = src[(size_t)(nh + 32 * j) * 128];

  int mt = mask[b * NN + t];
  int any = __syncthreads_or(mt);
  smask[t] = (t == 0 && !any) ? 1 : mt;
  __syncthreads();

  const float NEG = -3.4e38f;
  #pragma unroll
  for (int j = 0; j < 8; ++j)
    if (!smask[nh + 32 * j]) v[j] = (float4){NEG, NEG, NEG, NEG};

  // col max over this thread's 8 rows, then over the 32 nh groups via LDS
  float4 m4 = v[0];
  #pragma unroll
  for (int j = 1; j < 8; ++j) {
    m4.x = fmaxf(m4.x, v[j].x); m4.y = fmaxf(m4.y, v[j].y);
    m4.z = fmaxf(m4.z, v[j].z); m4.w = fmaxf(m4.w, v[j].w);
  }
  smx[nh][c8] = m4;
  __syncthreads();
  float4 mm = smx[0][c8];
  #pragma unroll
  for (int k = 1; k < 32; ++k) {
    float4 o = smx[k][c8];
    mm.x = fmaxf(mm.x, o.x); mm.y = fmaxf(mm.y, o.y);
    mm.z = fmaxf(mm.z, o.z); mm.w = fmaxf(mm.w, o.w);
  }

  // p = exp(v - m) in-register (single exp), col sum
  float4 s4 = {0.f, 0.f, 0.f, 0.f};
  #pragma unroll
  for (int j = 0; j < 8; ++j) {
    v[j].x = __expf(v[j].x - mm.x); s4.x += v[j].x;
    v[j].y = __expf(v[j].y - mm.y); s4.y += v[j].y;
    v[j].z = __expf(v[j].z - mm.z); s4.z += v[j].z;
    v[j].w = __expf(v[j].w - mm.w); s4.w += v[j].w;
  }
  sms[nh][c8] = s4;
  __syncthreads();
  float4 tot = sms[0][c8];
  #pragma unroll
  for (int k = 1; k < 32; ++k) {
    float4 o = sms[k][c8];
    tot.x += o.x; tot.y += o.y; tot.z += o.z; tot.w += o.w;
  }
  float4 inv = {1.f / tot.x, 1.f / tot.y, 1.f / tot.z, 1.f / tot.w};

  float4* dst = (float4*)(out + (((size_t)(b * NN)) << 9)) + oc * 8 + c8;
  #pragma unroll
  for (int j = 0; j < 8; ++j) {
    float4 r;
    r.x = v[j].x * inv.x;
    r.y = v[j].y * inv.y;
    r.z = v[j].z * inv.z;
    r.w = v[j].w * inv.w;
    dst[(size_t)(nh + 32 * j) * 128] = r;
  }
}

extern "C" void kernel_launch(void* const* d_in, const int* in_sizes, int n_in,
                              void* d_out, int out_size, void* d_ws, size_t ws_size,
                              hipStream_t stream) {
  const float* Obs = (const float*)d_in[0];
  const int*   msk = (const int*)d_in[1];
  const float* g1  = (const float*)d_in[2];
  const float* b1  = (const float*)d_in[3];
  const float* W1  = (const float*)d_in[4];
  const float* g2  = (const float*)d_in[5];
  const float* b2  = (const float*)d_in[6];
  const float* W2  = (const float*)d_in[7];
  const float* g3  = (const float*)d_in[8];
  const float* b3  = (const float*)d_in[9];
  const float* W3  = (const float*)d_in[10];
  float* out = (float*)d_out;

  char* ws = (char*)d_ws;
  const size_t MB = 1u << 20;
  float* Lg = (float*)ws;                  // [0, 64M) logits fp32
  f16*   WTc = (f16*)(ws + 64 * MB);       // 1.5 MB chunk-tiled

  prep_w_kernel<<<3072, 256, 0, stream>>>(W1, W2, W3, WTc);
  mega_kernel<<<1024, 512, 0, stream>>>(Obs, g1, b1, WTc, g2, b2, g3, b3, Lg);
  softmax_kernel<<<2048, 256, 0, stream>>>(Lg, msk, out);
}